// Round 5
// baseline (222.518 us; speedup 1.0000x reference)
//
#include <hip/hip_runtime.h>
#include <hip/hip_bf16.h>

// ---------------------------------------------------------------------------
// KroneNet fused kernel v5 for MI355X (gfx950)
// out[i][j] = softmax_j( s_a[i] * t_j[i] )
// History: v2 62us (parallel paths, 37MB spill) / v3 294us (seq paths, sched
// merged live ranges -> 440MB spill) / v4 46.5us (v2 + sched_barrier fences,
// spill = 0, occupancy-capped at 18.6%).
// v5: (a) 512-thread blocks, launch_bounds(512,4): 8 waves share one LDS
// image -> 2 blocks/CU = 16 waves/CU (50% cap vs 25%); (b) pack fused into
// the main kernel (block-local, from raw fp32 weights) -- no pack dispatch,
// no d_ws. Main loop identical to v4 (fences retained).
// ---------------------------------------------------------------------------

#define BTOT 262144
#define NBLK (BTOT / 512)   // 512 blocks x 512 samples (2 chunks of 256)

typedef __attribute__((ext_vector_type(4))) float floatx4;
typedef __attribute__((ext_vector_type(8))) short bf16x8;
typedef __attribute__((ext_vector_type(4))) int  intx4;

// LDS layout (bytes)
#define OFF_W2  0          // 2 paths * 4 ksteps * 8 ntiles * 64 lanes * 16B = 65536
#define OFF_W1  65536      // 2 paths * 144 * float4 (128 + 16 pad slots)    = 4608
#define OFF_B2  70144      // 2 paths * 128 * float                          = 1024
#define OFF_W3A 71168      // 128 * float                                    = 512
#define OFF_W3B 71680      // 3 * 128 * float                                = 1536
#define OFF_B3  73216      // {b3a, b3b0, b3b1, b3b2}                        = 16
#define WS_TOTAL 73232

// pack two fp32 -> one dword of two bf16 (round-half-up), 3 VALU ops
static __device__ __forceinline__ int pack2bf(float lo, float hi) {
    unsigned a = __builtin_bit_cast(unsigned, lo) + 0x8000u;
    unsigned b = __builtin_bit_cast(unsigned, hi) + 0x8000u;
    return (int)__builtin_amdgcn_perm(b, a, 0x07060302u); // {b.hi16, a.hi16}
}

// compile-time-indexed 4-way select (NO dynamic register indexing)
#define SEL4(a0, a1, a2, a3, i) \
    ((i) == 0 ? (a0) : (i) == 1 ? (a1) : (i) == 2 ? (a2) : (a3))

static __device__ __forceinline__ float redcol(float v) {
    v += __shfl_xor(v, 1); v += __shfl_xor(v, 2);
    v += __shfl_xor(v, 4); v += __shfl_xor(v, 8);
    return v;
}

// W1 slot with bank-conflict padding: one extra float4 slot every 8 entries
static __device__ __forceinline__ int w1slot(int k) { return k + (k >> 3); }

// ---------------------------------------------------------------------------
// Single fused kernel: 512 blocks x 512 threads (8 waves). Per block:
//   phase 0: pack weights into LDS (W2 -> MFMA B-frag order: lane l holds
//            B[k = quad*8 + j][n = col], verified rounds 1-4)
//   phase 1: per-wave 32 samples x 2 chunks, barrier-free (v4 structure)
// ---------------------------------------------------------------------------
__global__ __launch_bounds__(512, 4)
void krone_main(const float* __restrict__ x,
                const float* __restrict__ w1a, const float* __restrict__ w1b,
                const float* __restrict__ b1a, const float* __restrict__ b1b,
                const float* __restrict__ w2a, const float* __restrict__ w2b,
                const float* __restrict__ b2a, const float* __restrict__ b2b,
                const float* __restrict__ w3a, const float* __restrict__ w3b,
                const float* __restrict__ b3a, const float* __restrict__ b3b,
                float* __restrict__ out) {
    __shared__ __align__(16) unsigned char smem[WS_TOTAL];
    __shared__ float4 sEx[8][32];

    const int tid = threadIdx.x;

    // ---- phase 0: block-local weight pack ----
    {
        // W2 both paths: 8192 float4 groups, coalesced global float4 reads.
        // (n, k..k+3) -> LDS path*32768 + (s*8+t)*1024 + l*16 + (k&7)*2
        //   s = k>>5, quad = (k&31)>>3, t = n>>4, l = quad*16 + (n&15)
        #pragma unroll
        for (int i = 0; i < 16; ++i) {
            int u = i * 512 + tid;
            int path = u >> 12;
            int v = u & 4095;
            int n = v >> 5;
            int k4 = v & 31;
            const float4* w2p = (const float4*)(path ? w2b : w2a);
            float4 f = w2p[n * 32 + k4];
            int k = k4 * 4;
            int s = k >> 5;
            int quad = (k & 31) >> 3;
            int j0 = k & 7;                 // 0 or 4
            int tt = n >> 4;
            int l = quad * 16 + (n & 15);
            int2 pkd;
            pkd.x = pack2bf(f.x, f.y);
            pkd.y = pack2bf(f.z, f.w);
            *(int2*)(smem + OFF_W2 + path * 32768 + (s * 8 + tt) * 1024 + l * 16 + j0 * 2) = pkd;
        }
        if (tid < 256) {
            int pth = tid >> 7, kk = tid & 127;
            const float* w1 = pth ? w1b : w1a;
            const float* b1 = pth ? b1b : b1a;
            ((float4*)(smem + OFF_W1))[pth * 144 + w1slot(kk)] =
                make_float4(w1[2 * kk], w1[2 * kk + 1], b1[kk], 0.f);
            ((float*)(smem + OFF_B2))[tid] = (pth ? b2b : b2a)[kk];
        } else if (tid < 384) {
            ((float*)(smem + OFF_W3A))[tid - 256] = w3a[tid - 256];
        }
        if (tid >= 128) {   // 384 entries of w3b
            ((float*)(smem + OFF_W3B))[tid - 128] = w3b[tid - 128];
        }
        if (tid == 0) {
            float* d = (float*)(smem + OFF_B3);
            d[0] = b3a[0]; d[1] = b3b[0]; d[2] = b3b[1]; d[3] = b3b[2];
        }
    }
    __syncthreads();

    // ---- phase 1: main compute (v4 structure, 8 waves) ----
    const int lane = tid & 63;
    const int wave = tid >> 6;
    const int quad = lane >> 4;
    const int col  = lane & 15;

    const bf16x8* W2A = (const bf16x8*)(smem + OFF_W2);
    const bf16x8* W2B = (const bf16x8*)(smem + OFF_W2 + 32768);
    const float4* W1A = (const float4*)(smem + OFF_W1);
    const float4* W1B = W1A + 144;
    const float*  B2A = (const float*)(smem + OFF_B2);
    const float*  B2B = B2A + 128;
    const float*  W3A = (const float*)(smem + OFF_W3A);
    const float*  W3B = (const float*)(smem + OFF_W3B);
    const float*  B3  = (const float*)(smem + OFF_B3);
    const float2* xA  = (const float2*)x;
    const float2* xB  = xA + BTOT;

    #pragma unroll
    for (int c = 0; c < 2; ++c) {
        __builtin_amdgcn_sched_barrier(0);   // fence: no cross-chunk merging
        const int base = blockIdx.x * 512 + c * 256 + wave * 32;

        float2 xa[2], xb[2];
        #pragma unroll
        for (int mt = 0; mt < 2; ++mt) {
            xa[mt] = xA[base + mt * 16 + col];
            xb[mt] = xB[base + mt * 16 + col];
        }

        floatx4 accA[8][2], accB[8][2];
        #pragma unroll
        for (int t = 0; t < 8; ++t)
            #pragma unroll
            for (int mt = 0; mt < 2; ++mt) {
                accA[t][mt] = (floatx4){0.f, 0.f, 0.f, 0.f};
                accB[t][mt] = (floatx4){0.f, 0.f, 0.f, 0.f};
            }

        #pragma unroll
        for (int s = 0; s < 4; ++s) {
            // A-fragments on the fly: lane holds A[m=col][k=s*32+quad*8+j]
            intx4 afA[2], afB[2];
            const int bslot = s * 36 + quad * 9;   // padded W1 slot base
            #pragma unroll
            for (int j2 = 0; j2 < 4; ++j2) {
                float4 a0 = W1A[bslot + 2 * j2];
                float4 a1 = W1A[bslot + 2 * j2 + 1];
                float4 b0 = W1B[bslot + 2 * j2];
                float4 b1 = W1B[bslot + 2 * j2 + 1];
                #pragma unroll
                for (int mt = 0; mt < 2; ++mt) {
                    float ha0 = fmaxf(fmaf(xa[mt].x, a0.x, fmaf(xa[mt].y, a0.y, a0.z)), 0.f);
                    float ha1 = fmaxf(fmaf(xa[mt].x, a1.x, fmaf(xa[mt].y, a1.y, a1.z)), 0.f);
                    float hb0 = fmaxf(fmaf(xb[mt].x, b0.x, fmaf(xb[mt].y, b0.y, b0.z)), 0.f);
                    float hb1 = fmaxf(fmaf(xb[mt].x, b1.x, fmaf(xb[mt].y, b1.y, b1.z)), 0.f);
                    afA[mt][j2] = pack2bf(ha0, ha1);
                    afB[mt][j2] = pack2bf(hb0, hb1);
                }
            }
            #pragma unroll
            for (int t = 0; t < 8; ++t) {
                bf16x8 bfa = W2A[(s * 8 + t) * 64 + lane];
                bf16x8 bfb = W2B[(s * 8 + t) * 64 + lane];
                #pragma unroll
                for (int mt = 0; mt < 2; ++mt) {
                    accA[t][mt] = __builtin_amdgcn_mfma_f32_16x16x32_bf16(
                        __builtin_bit_cast(bf16x8, afA[mt]), bfa, accA[t][mt], 0, 0, 0);
                    accB[t][mt] = __builtin_amdgcn_mfma_f32_16x16x32_bf16(
                        __builtin_bit_cast(bf16x8, afB[mt]), bfb, accB[t][mt], 0, 0, 0);
                }
            }
        }
        __builtin_amdgcn_sched_barrier(0);   // fence: MFMA loop | epilogue

        // Epilogue. C layout: (t, mt, r) -> sample mt*16 + quad*4 + r, n = t*16+col.
        float pa[2][4]  = {};
        float pb0[2][4] = {}, pb1[2][4] = {}, pb2[2][4] = {};
        #pragma unroll
        for (int t = 0; t < 8; ++t) {
            int n = t * 16 + col;
            float b2a_ = B2A[n], w3a_ = W3A[n];
            float b2b_ = B2B[n];
            float w30 = W3B[n], w31 = W3B[128 + n], w32 = W3B[256 + n];
            #pragma unroll
            for (int mt = 0; mt < 2; ++mt)
                #pragma unroll
                for (int r = 0; r < 4; ++r) {
                    float ha = fmaxf(accA[t][mt][r] + b2a_, 0.f);
                    pa[mt][r] = fmaf(w3a_, ha, pa[mt][r]);
                    float hb = fmaxf(accB[t][mt][r] + b2b_, 0.f);
                    pb0[mt][r] = fmaf(w30, hb, pb0[mt][r]);
                    pb1[mt][r] = fmaf(w31, hb, pb1[mt][r]);
                    pb2[mt][r] = fmaf(w32, hb, pb2[mt][r]);
                }
        }
        #pragma unroll
        for (int mt = 0; mt < 2; ++mt)
            #pragma unroll
            for (int r = 0; r < 4; ++r) {
                pa[mt][r]  = redcol(pa[mt][r]);
                pb0[mt][r] = redcol(pb0[mt][r]);
                pb1[mt][r] = redcol(pb1[mt][r]);
                pb2[mt][r] = redcol(pb2[mt][r]);
            }
        __builtin_amdgcn_sched_barrier(0);   // fence: reductions | exchange

        if (col < 4) {
            float b3a_ = B3[0], b30 = B3[1], b31 = B3[2], b32 = B3[3];
            #pragma unroll
            for (int mt = 0; mt < 2; ++mt) {
                int sl = mt * 16 + quad * 4 + col;
                float va = SEL4(pa[mt][0],  pa[mt][1],  pa[mt][2],  pa[mt][3],  col) + b3a_;
                float v0 = SEL4(pb0[mt][0], pb0[mt][1], pb0[mt][2], pb0[mt][3], col) + b30;
                float v1 = SEL4(pb1[mt][0], pb1[mt][1], pb1[mt][2], pb1[mt][3], col) + b31;
                float v2 = SEL4(pb2[mt][0], pb2[mt][1], pb2[mt][2], pb2[mt][3], col) + b32;
                sEx[wave][sl] = make_float4(va, v0, v1, v2);
            }
        }
        // same-wave LDS RAW: ordered by lgkmcnt, no barrier needed
        if (lane < 32) {
            float4 v = sEx[wave][lane];
            float y0 = v.x * v.y, y1 = v.x * v.z, y2 = v.x * v.w;
            float m = fmaxf(y0, fmaxf(y1, y2));
            float e0 = __expf(y0 - m), e1 = __expf(y1 - m), e2 = __expf(y2 - m);
            float rs = 1.f / (e0 + e1 + e2);
            long o = (long)(base + lane) * 3;
            out[o]     = e0 * rs;
            out[o + 1] = e1 * rs;
            out[o + 2] = e2 * rs;
        }
        __builtin_amdgcn_sched_barrier(0);   // fence: chunk end
    }
}

extern "C" void kernel_launch(void* const* d_in, const int* in_sizes, int n_in,
                              void* d_out, int out_size, void* d_ws, size_t ws_size,
                              hipStream_t stream) {
    const float* x   = (const float*)d_in[0];
    const float* w1a = (const float*)d_in[1];
    const float* w1b = (const float*)d_in[2];
    const float* b1a = (const float*)d_in[3];
    const float* b1b = (const float*)d_in[4];
    const float* w2a = (const float*)d_in[5];
    const float* w2b = (const float*)d_in[6];
    const float* b2a = (const float*)d_in[7];
    const float* b2b = (const float*)d_in[8];
    const float* w3a = (const float*)d_in[9];
    const float* w3b = (const float*)d_in[10];
    const float* b3a = (const float*)d_in[11];
    const float* b3b = (const float*)d_in[12];
    float* out = (float*)d_out;

    krone_main<<<NBLK, 512, 0, stream>>>(x, w1a, w1b, b1a, b1b, w2a, w2b,
                                         b2a, b2b, w3a, w3b, b3a, b3b, out);
}

// Round 6
// 119.290 us; speedup vs baseline: 1.8654x; 1.8654x over previous
//
#include <hip/hip_runtime.h>
#include <hip/hip_bf16.h>

// ---------------------------------------------------------------------------
// KroneNet fused kernels v6 for MI355X (gfx950)
// out[i][j] = softmax_j( s_a[i] * t_j[i] )
// History: v4 46.5us (dual-path fused, 0 spill, 2 waves/SIMD: LDS 75KB AND
// 188 unified regs/wave both bind). v5 151us (launch_bounds(512,4) capped
// unified regs at 128 < 128 accs + working set -> 380MB spill. LESSON:
// VGPR+AGPR share one file; never cap below acc footprint).
// v6: split by path. Kernel A (path a) -> s_a to d_ws; kernel B (path b)
// reads s_a, computes softmax. Each kernel: 36KB LDS (4 blocks/CU), 64 AGPR
// + ~90 VGPR (~155/wave -> 3 waves/SIMD). Fences + padded W1 + verified
// pack mapping retained. b2 folded into acc init.
// ---------------------------------------------------------------------------

#define BTOT 262144
#define NBLK (BTOT / 256)   // 1024 blocks x 256 samples (2 chunks of 128)

typedef __attribute__((ext_vector_type(4))) float floatx4;
typedef __attribute__((ext_vector_type(8))) short bf16x8;
typedef __attribute__((ext_vector_type(4))) int  intx4;

// per-kernel LDS layout (bytes), single path
#define OFF_W2  0          // 4 ksteps * 8 ntiles * 64 lanes * 16B = 32768
#define OFF_W1  32768      // 144 * float4 (128 + 16 pad slots)    = 2304
#define OFF_B2  35072      // 128 * float                          = 512
#define OFF_W3  35584      // 128 * float (A) or 384 * float (B)

// pack two fp32 -> one dword of two bf16 (round-half-up), 3 VALU ops
static __device__ __forceinline__ int pack2bf(float lo, float hi) {
    unsigned a = __builtin_bit_cast(unsigned, lo) + 0x8000u;
    unsigned b = __builtin_bit_cast(unsigned, hi) + 0x8000u;
    return (int)__builtin_amdgcn_perm(b, a, 0x07060302u); // {b.hi16, a.hi16}
}

// compile-time-indexed 4-way select (NO dynamic register indexing)
#define SEL4(a0, a1, a2, a3, i) \
    ((i) == 0 ? (a0) : (i) == 1 ? (a1) : (i) == 2 ? (a2) : (a3))

static __device__ __forceinline__ float redcol(float v) {
    v += __shfl_xor(v, 1); v += __shfl_xor(v, 2);
    v += __shfl_xor(v, 4); v += __shfl_xor(v, 8);
    return v;
}

// W1 slot with bank-conflict padding: one extra float4 slot every 8 entries
static __device__ __forceinline__ int w1slot(int k) { return k + (k >> 3); }

// Shared phase-0: pack one path's weights into LDS.
// W2 mapping (verified v5, passed correctness): float4 group u = n*32+k4,
// k = 4*k4: dest = (s*8+t)*1024 + l*16 + (k&7)*2, s=k>>5, l=((k&31)>>3)*16
// + (n&15), t = n>>4.  B-frag: lane holds B[k=quad*8+j][n=col].
static __device__ __forceinline__ void pack_path(
        unsigned char* smem, int tid,
        const float* __restrict__ w2, const float* __restrict__ w1,
        const float* __restrict__ b1, const float* __restrict__ b2) {
    const float4* w2p = (const float4*)w2;
    #pragma unroll
    for (int i = 0; i < 16; ++i) {
        int u = i * 256 + tid;        // u = n*32 + k4
        int n = u >> 5;
        float4 f = w2p[u];
        int k = (u & 31) * 4;
        int s = k >> 5;
        int j0 = k & 7;               // 0 or 4
        int l = ((k & 31) >> 3) * 16 + (n & 15);
        int2 pkd;
        pkd.x = pack2bf(f.x, f.y);
        pkd.y = pack2bf(f.z, f.w);
        *(int2*)(smem + OFF_W2 + (s * 8 + (n >> 4)) * 1024 + l * 16 + j0 * 2) = pkd;
    }
    if (tid < 128) {
        ((float4*)(smem + OFF_W1))[w1slot(tid)] =
            make_float4(w1[2 * tid], w1[2 * tid + 1], b1[tid], 0.f);
        ((float*)(smem + OFF_B2))[tid] = b2[tid];
    }
}

// Shared main GEMM body: computes relu(W2.relu(W1.x+b1)+b2) accumulator for
// one chunk of 32 samples (acc pre-initialized with b2; caller applies relu
// in its epilogue). acc layout: (t, mt, r) -> sample mt*16+quad*4+r,
// n = t*16+col.
#define GEMM_CHUNK(acc, xv, W1p, W2p, B2p)                                     \
    {                                                                          \
        _Pragma("unroll")                                                      \
        for (int t = 0; t < 8; ++t) {                                          \
            float b2n = (B2p)[t * 16 + col];                                   \
            floatx4 bi = (floatx4){b2n, b2n, b2n, b2n};                        \
            _Pragma("unroll")                                                  \
            for (int mt = 0; mt < 2; ++mt) acc[t][mt] = bi;                    \
        }                                                                      \
        _Pragma("unroll")                                                      \
        for (int s = 0; s < 4; ++s) {                                          \
            intx4 af[2];                                                       \
            const int bslot = s * 36 + quad * 9;                               \
            _Pragma("unroll")                                                  \
            for (int j2 = 0; j2 < 4; ++j2) {                                   \
                float4 c0 = (W1p)[bslot + 2 * j2];                             \
                float4 c1 = (W1p)[bslot + 2 * j2 + 1];                         \
                _Pragma("unroll")                                              \
                for (int mt = 0; mt < 2; ++mt) {                               \
                    float h0 = fmaxf(fmaf(xv[mt].x, c0.x,                      \
                                fmaf(xv[mt].y, c0.y, c0.z)), 0.f);             \
                    float h1 = fmaxf(fmaf(xv[mt].x, c1.x,                      \
                                fmaf(xv[mt].y, c1.y, c1.z)), 0.f);             \
                    af[mt][j2] = pack2bf(h0, h1);                              \
                }                                                              \
            }                                                                  \
            _Pragma("unroll")                                                  \
            for (int t = 0; t < 8; ++t) {                                      \
                bf16x8 bfr = (W2p)[(s * 8 + t) * 64 + lane];                   \
                _Pragma("unroll")                                              \
                for (int mt = 0; mt < 2; ++mt)                                 \
                    acc[t][mt] = __builtin_amdgcn_mfma_f32_16x16x32_bf16(      \
                        __builtin_bit_cast(bf16x8, af[mt]), bfr,               \
                        acc[t][mt], 0, 0, 0);                                  \
            }                                                                  \
        }                                                                      \
    }

// ---------------------------------------------------------------------------
// Kernel A: path a -> s_a[sample] into d_ws (fp32, 1 MB)
// ---------------------------------------------------------------------------
__global__ __launch_bounds__(256, 2)
void krone_a(const float* __restrict__ x,
             const float* __restrict__ w1a, const float* __restrict__ b1a,
             const float* __restrict__ w2a, const float* __restrict__ b2a,
             const float* __restrict__ w3a, const float* __restrict__ b3a,
             float* __restrict__ sa_out) {
    __shared__ __align__(16) unsigned char smem[36096];
    const int tid = threadIdx.x;
    pack_path(smem, tid, w2a, w1a, b1a, b2a);
    if (tid < 128) ((float*)(smem + OFF_W3))[tid] = w3a[tid];
    __syncthreads();

    const int lane = tid & 63;
    const int wave = tid >> 6;
    const int quad = lane >> 4;
    const int col  = lane & 15;
    const bf16x8* W2 = (const bf16x8*)(smem + OFF_W2);
    const float4* W1 = (const float4*)(smem + OFF_W1);
    const float*  B2 = (const float*)(smem + OFF_B2);
    const float*  W3 = (const float*)(smem + OFF_W3);
    const float2* xp = (const float2*)x;           // path a = x[0]
    const float b3 = b3a[0];

    #pragma unroll
    for (int c = 0; c < 2; ++c) {
        __builtin_amdgcn_sched_barrier(0);
        const int base = blockIdx.x * 256 + c * 128 + wave * 32;
        float2 xv[2];
        #pragma unroll
        for (int mt = 0; mt < 2; ++mt) xv[mt] = xp[base + mt * 16 + col];

        floatx4 acc[8][2];
        GEMM_CHUNK(acc, xv, W1, W2, B2);
        __builtin_amdgcn_sched_barrier(0);

        float pa[2][4] = {};
        #pragma unroll
        for (int t = 0; t < 8; ++t) {
            float w3n = W3[t * 16 + col];
            #pragma unroll
            for (int mt = 0; mt < 2; ++mt)
                #pragma unroll
                for (int r = 0; r < 4; ++r)
                    pa[mt][r] = fmaf(w3n, fmaxf(acc[t][mt][r], 0.f), pa[mt][r]);
        }
        #pragma unroll
        for (int mt = 0; mt < 2; ++mt)
            #pragma unroll
            for (int r = 0; r < 4; ++r) pa[mt][r] = redcol(pa[mt][r]);
        __builtin_amdgcn_sched_barrier(0);

        if (col < 4) {
            #pragma unroll
            for (int mt = 0; mt < 2; ++mt) {
                int sl = mt * 16 + quad * 4 + col;
                sa_out[base + sl] =
                    SEL4(pa[mt][0], pa[mt][1], pa[mt][2], pa[mt][3], col) + b3;
            }
        }
        __builtin_amdgcn_sched_barrier(0);
    }
}

// ---------------------------------------------------------------------------
// Kernel B: path b -> t0,t1,t2; reads s_a from d_ws; softmax -> out
// ---------------------------------------------------------------------------
__global__ __launch_bounds__(256, 2)
void krone_b(const float* __restrict__ x,
             const float* __restrict__ w1b, const float* __restrict__ b1b,
             const float* __restrict__ w2b, const float* __restrict__ b2b,
             const float* __restrict__ w3b, const float* __restrict__ b3b,
             const float* __restrict__ sa_in, float* __restrict__ out) {
    __shared__ __align__(16) unsigned char smem[37120];
    const int tid = threadIdx.x;
    pack_path(smem, tid, w2b, w1b, b1b, b2b);
    for (int i = tid; i < 384; i += 256) ((float*)(smem + OFF_W3))[i] = w3b[i];
    __syncthreads();

    const int lane = tid & 63;
    const int wave = tid >> 6;
    const int quad = lane >> 4;
    const int col  = lane & 15;
    const bf16x8* W2 = (const bf16x8*)(smem + OFF_W2);
    const float4* W1 = (const float4*)(smem + OFF_W1);
    const float*  B2 = (const float*)(smem + OFF_B2);
    const float*  W3 = (const float*)(smem + OFF_W3);
    const float2* xp = (const float2*)x + BTOT;    // path b = x[1]
    const float b30 = b3b[0], b31 = b3b[1], b32 = b3b[2];

    #pragma unroll
    for (int c = 0; c < 2; ++c) {
        __builtin_amdgcn_sched_barrier(0);
        const int base = blockIdx.x * 256 + c * 128 + wave * 32;
        float2 xv[2];
        #pragma unroll
        for (int mt = 0; mt < 2; ++mt) xv[mt] = xp[base + mt * 16 + col];

        floatx4 acc[8][2];
        GEMM_CHUNK(acc, xv, W1, W2, B2);
        __builtin_amdgcn_sched_barrier(0);

        float p0[2][4] = {}, p1[2][4] = {}, p2[2][4] = {};
        #pragma unroll
        for (int t = 0; t < 8; ++t) {
            int n = t * 16 + col;
            float w30 = W3[n], w31 = W3[128 + n], w32 = W3[256 + n];
            #pragma unroll
            for (int mt = 0; mt < 2; ++mt)
                #pragma unroll
                for (int r = 0; r < 4; ++r) {
                    float h = fmaxf(acc[t][mt][r], 0.f);
                    p0[mt][r] = fmaf(w30, h, p0[mt][r]);
                    p1[mt][r] = fmaf(w31, h, p1[mt][r]);
                    p2[mt][r] = fmaf(w32, h, p2[mt][r]);
                }
        }
        #pragma unroll
        for (int mt = 0; mt < 2; ++mt)
            #pragma unroll
            for (int r = 0; r < 4; ++r) {
                p0[mt][r] = redcol(p0[mt][r]);
                p1[mt][r] = redcol(p1[mt][r]);
                p2[mt][r] = redcol(p2[mt][r]);
            }
        __builtin_amdgcn_sched_barrier(0);

        if (col < 4) {
            #pragma unroll
            for (int mt = 0; mt < 2; ++mt) {
                int sl = mt * 16 + quad * 4 + col;
                float t0 = SEL4(p0[mt][0], p0[mt][1], p0[mt][2], p0[mt][3], col) + b30;
                float t1 = SEL4(p1[mt][0], p1[mt][1], p1[mt][2], p1[mt][3], col) + b31;
                float t2 = SEL4(p2[mt][0], p2[mt][1], p2[mt][2], p2[mt][3], col) + b32;
                float sa = sa_in[base + sl];
                float y0 = sa * t0, y1 = sa * t1, y2 = sa * t2;
                float m = fmaxf(y0, fmaxf(y1, y2));
                float e0 = __expf(y0 - m), e1 = __expf(y1 - m), e2 = __expf(y2 - m);
                float rs = 1.f / (e0 + e1 + e2);
                long o = (long)(base + sl) * 3;
                out[o]     = e0 * rs;
                out[o + 1] = e1 * rs;
                out[o + 2] = e2 * rs;
            }
        }
        __builtin_amdgcn_sched_barrier(0);
    }
}

extern "C" void kernel_launch(void* const* d_in, const int* in_sizes, int n_in,
                              void* d_out, int out_size, void* d_ws, size_t ws_size,
                              hipStream_t stream) {
    const float* x   = (const float*)d_in[0];
    const float* w1a = (const float*)d_in[1];
    const float* w1b = (const float*)d_in[2];
    const float* b1a = (const float*)d_in[3];
    const float* b1b = (const float*)d_in[4];
    const float* w2a = (const float*)d_in[5];
    const float* w2b = (const float*)d_in[6];
    const float* b2a = (const float*)d_in[7];
    const float* b2b = (const float*)d_in[8];
    const float* w3a = (const float*)d_in[9];
    const float* w3b = (const float*)d_in[10];
    const float* b3a = (const float*)d_in[11];
    const float* b3b = (const float*)d_in[12];
    float* sa = (float*)d_ws;          // 1 MB: s_a per sample
    float* out = (float*)d_out;

    krone_a<<<NBLK, 256, 0, stream>>>(x, w1a, b1a, w2a, b2a, w3a, b3a, sa);
    krone_b<<<NBLK, 256, 0, stream>>>(x, w1b, b1b, w2b, b2b, w3b, b3b, sa, out);
}